// Round 1
// baseline (727.840 us; speedup 1.0000x reference)
//
#include <hip/hip_runtime.h>
#include <math.h>

#define D_MODEL 512
#define NHEADS 8
#define DK 64
#define DFFN 2048

// ---------------- LayerNorm (one block per row, D=512, 256 threads) ----------------
__global__ __launch_bounds__(256) void ln_kernel(
    const float* __restrict__ x, const float* __restrict__ alpha,
    const float* __restrict__ beta, float* __restrict__ y) {
  int row = blockIdx.x;
  int t = threadIdx.x;
  const float* xr = x + (size_t)row * D_MODEL;
  float2 v = ((const float2*)xr)[t];
  __shared__ float rs[256], rq[256];
  rs[t] = v.x + v.y;
  rq[t] = v.x * v.x + v.y * v.y;
  __syncthreads();
  for (int o = 128; o > 0; o >>= 1) {
    if (t < o) { rs[t] += rs[t + o]; rq[t] += rq[t + o]; }
    __syncthreads();
  }
  float mu = rs[0] * (1.0f / D_MODEL);
  // ddof=1 sample variance; denominator is (sd + eps), matching jnp.std + EPS
  float var = (rq[0] - (float)D_MODEL * mu * mu) * (1.0f / (D_MODEL - 1));
  float inv = 1.0f / (sqrtf(fmaxf(var, 0.0f)) + 1e-6f);
  float2 a2 = ((const float2*)alpha)[t];
  float2 b2 = ((const float2*)beta)[t];
  float2 o2;
  o2.x = a2.x * (v.x - mu) * inv + b2.x;
  o2.y = a2.y * (v.y - mu) * inv + b2.y;
  ((float2*)(y + (size_t)row * D_MODEL))[t] = o2;
}

// ---------------- Generic fp32 GEMM: C[m,n] = sum_k A[m,k]*B[n,k] + bias[n] (+res)(+relu)
// 64x64 tile, BK=16, 256 threads, 4x4 per thread.
template <int RELU>
__global__ __launch_bounds__(256) void gemm_nt(
    const float* __restrict__ A, const float* __restrict__ B,
    const float* __restrict__ bias, const float* __restrict__ res,
    float* __restrict__ C, int M, int N, int K) {
  __shared__ float As[16][65];
  __shared__ float Bs[16][65];
  int t = threadIdx.x;
  int tx = t & 15, ty = t >> 4;
  int ldRow = t >> 2;          // 0..63
  int ldCol = (t & 3) << 2;    // 0,4,8,12
  const float* Ap = A + (size_t)(blockIdx.y * 64 + ldRow) * K + ldCol;
  const float* Bp = B + (size_t)(blockIdx.x * 64 + ldRow) * K + ldCol;
  float acc[4][4] = {};
  for (int k0 = 0; k0 < K; k0 += 16) {
    float4 a4 = *(const float4*)(Ap + k0);
    float4 b4 = *(const float4*)(Bp + k0);
    As[ldCol + 0][ldRow] = a4.x; As[ldCol + 1][ldRow] = a4.y;
    As[ldCol + 2][ldRow] = a4.z; As[ldCol + 3][ldRow] = a4.w;
    Bs[ldCol + 0][ldRow] = b4.x; Bs[ldCol + 1][ldRow] = b4.y;
    Bs[ldCol + 2][ldRow] = b4.z; Bs[ldCol + 3][ldRow] = b4.w;
    __syncthreads();
#pragma unroll
    for (int kk = 0; kk < 16; ++kk) {
      float a[4], b[4];
#pragma unroll
      for (int i = 0; i < 4; ++i) a[i] = As[kk][ty * 4 + i];
#pragma unroll
      for (int j = 0; j < 4; ++j) b[j] = Bs[kk][tx * 4 + j];
#pragma unroll
      for (int i = 0; i < 4; ++i)
#pragma unroll
        for (int j = 0; j < 4; ++j) acc[i][j] += a[i] * b[j];
    }
    __syncthreads();
  }
  int row0 = blockIdx.y * 64 + ty * 4;
  int col0 = blockIdx.x * 64 + tx * 4;
#pragma unroll
  for (int i = 0; i < 4; ++i) {
#pragma unroll
    for (int j = 0; j < 4; ++j) {
      float v = acc[i][j] + bias[col0 + j];
      if (res) v += res[(size_t)(row0 + i) * N + col0 + j];
      if (RELU) v = fmaxf(v, 0.0f);
      C[(size_t)(row0 + i) * N + col0 + j] = v;
    }
  }
}

// ---------------- Fused Q/K/V projection: blockIdx.z selects weight/bias/output
struct Triple { const float* B; const float* bias; float* C; };
struct Triple3 { Triple t[3]; };

__global__ __launch_bounds__(256) void gemm_qkv(
    const float* __restrict__ A, Triple3 p3, int M, int N, int K) {
  Triple tr = p3.t[blockIdx.z];
  const float* __restrict__ B = tr.B;
  __shared__ float As[16][65];
  __shared__ float Bs[16][65];
  int t = threadIdx.x;
  int tx = t & 15, ty = t >> 4;
  int ldRow = t >> 2;
  int ldCol = (t & 3) << 2;
  const float* Ap = A + (size_t)(blockIdx.y * 64 + ldRow) * K + ldCol;
  const float* Bp = B + (size_t)(blockIdx.x * 64 + ldRow) * K + ldCol;
  float acc[4][4] = {};
  for (int k0 = 0; k0 < K; k0 += 16) {
    float4 a4 = *(const float4*)(Ap + k0);
    float4 b4 = *(const float4*)(Bp + k0);
    As[ldCol + 0][ldRow] = a4.x; As[ldCol + 1][ldRow] = a4.y;
    As[ldCol + 2][ldRow] = a4.z; As[ldCol + 3][ldRow] = a4.w;
    Bs[ldCol + 0][ldRow] = b4.x; Bs[ldCol + 1][ldRow] = b4.y;
    Bs[ldCol + 2][ldRow] = b4.z; Bs[ldCol + 3][ldRow] = b4.w;
    __syncthreads();
#pragma unroll
    for (int kk = 0; kk < 16; ++kk) {
      float a[4], b[4];
#pragma unroll
      for (int i = 0; i < 4; ++i) a[i] = As[kk][ty * 4 + i];
#pragma unroll
      for (int j = 0; j < 4; ++j) b[j] = Bs[kk][tx * 4 + j];
#pragma unroll
      for (int i = 0; i < 4; ++i)
#pragma unroll
        for (int j = 0; j < 4; ++j) acc[i][j] += a[i] * b[j];
    }
    __syncthreads();
  }
  int row0 = blockIdx.y * 64 + ty * 4;
  int col0 = blockIdx.x * 64 + tx * 4;
#pragma unroll
  for (int i = 0; i < 4; ++i) {
#pragma unroll
    for (int j = 0; j < 4; ++j) {
      tr.C[(size_t)(row0 + i) * N + col0 + j] = acc[i][j] + tr.bias[col0 + j];
    }
  }
}

// ---------------- Split-K GEMM (raw partials, no epilogue), blockIdx.z = K chunk
__global__ __launch_bounds__(256) void gemm_nt_splitk(
    const float* __restrict__ A, const float* __restrict__ B,
    float* __restrict__ P, int M, int N, int K, int KC) {
  __shared__ float As[16][65];
  __shared__ float Bs[16][65];
  int t = threadIdx.x;
  int tx = t & 15, ty = t >> 4;
  int ldRow = t >> 2;
  int ldCol = (t & 3) << 2;
  int kbase = blockIdx.z * KC;
  const float* Ap = A + (size_t)(blockIdx.y * 64 + ldRow) * K + ldCol + kbase;
  const float* Bp = B + (size_t)(blockIdx.x * 64 + ldRow) * K + ldCol + kbase;
  float acc[4][4] = {};
  for (int k0 = 0; k0 < KC; k0 += 16) {
    float4 a4 = *(const float4*)(Ap + k0);
    float4 b4 = *(const float4*)(Bp + k0);
    As[ldCol + 0][ldRow] = a4.x; As[ldCol + 1][ldRow] = a4.y;
    As[ldCol + 2][ldRow] = a4.z; As[ldCol + 3][ldRow] = a4.w;
    Bs[ldCol + 0][ldRow] = b4.x; Bs[ldCol + 1][ldRow] = b4.y;
    Bs[ldCol + 2][ldRow] = b4.z; Bs[ldCol + 3][ldRow] = b4.w;
    __syncthreads();
#pragma unroll
    for (int kk = 0; kk < 16; ++kk) {
      float a[4], b[4];
#pragma unroll
      for (int i = 0; i < 4; ++i) a[i] = As[kk][ty * 4 + i];
#pragma unroll
      for (int j = 0; j < 4; ++j) b[j] = Bs[kk][tx * 4 + j];
#pragma unroll
      for (int i = 0; i < 4; ++i)
#pragma unroll
        for (int j = 0; j < 4; ++j) acc[i][j] += a[i] * b[j];
    }
    __syncthreads();
  }
  int row0 = blockIdx.y * 64 + ty * 4;
  int col0 = blockIdx.x * 64 + tx * 4;
  float* Pz = P + (size_t)blockIdx.z * M * N;
#pragma unroll
  for (int i = 0; i < 4; ++i)
#pragma unroll
    for (int j = 0; j < 4; ++j)
      Pz[(size_t)(row0 + i) * N + col0 + j] = acc[i][j];
}

__global__ __launch_bounds__(256) void splitk_reduce(
    const float* __restrict__ P, const float* __restrict__ bias,
    const float* __restrict__ res, float* __restrict__ C,
    int MN, int N, int Z) {
  int idx = blockIdx.x * 256 + threadIdx.x;
  if (idx >= MN) return;
  float v = bias[idx % N] + res[idx];
  for (int z = 0; z < Z; ++z) v += P[(size_t)z * MN + idx];
  C[idx] = v;
}

// ---------------- Attention: one block per (b, h, i). s must be 256.
__global__ __launch_bounds__(256) void attn_kernel(
    const float* __restrict__ q, const float* __restrict__ k,
    const float* __restrict__ v, const float* __restrict__ cbk,
    const float* __restrict__ cbv, const int* __restrict__ mask,
    float* __restrict__ concat, int s) {
  int i = blockIdx.x % s;
  int h = (blockIdx.x / s) % NHEADS;
  int b = blockIdx.x / (s * NHEADS);
  int t = threadIdx.x;

  __shared__ __align__(16) float qs[DK];
  __shared__ float p[256];
  __shared__ float red[256];
  __shared__ float outp[4][DK];

  size_t qbase = ((size_t)(b * s + i)) * D_MODEL + h * DK;
  if (t < DK) qs[t] = q[qbase + t];
  __syncthreads();

  // Phase A: scores[j] = (q_i . k_j + q_i . cbk[b,j,i,h,:]) / 8
  int lane16 = t & 15;
  int jg = t >> 4;  // 0..15
  float4 q4 = ((const float4*)qs)[lane16];
  for (int jt = 0; jt < s; jt += 16) {
    int j = jt + jg;
    size_t kb = ((size_t)(b * s + j)) * D_MODEL + h * DK + lane16 * 4;
    float4 k4 = *(const float4*)(k + kb);
    size_t bb = (((size_t)(b * s + j)) * s + i) * D_MODEL + h * DK + lane16 * 4;
    float4 b4 = *(const float4*)(cbk + bb);
    float part = q4.x * (k4.x + b4.x) + q4.y * (k4.y + b4.y) +
                 q4.z * (k4.z + b4.z) + q4.w * (k4.w + b4.w);
    part += __shfl_xor(part, 1);
    part += __shfl_xor(part, 2);
    part += __shfl_xor(part, 4);
    part += __shfl_xor(part, 8);
    if (lane16 == 0) p[j] = part * 0.125f;
  }
  __syncthreads();

  // Softmax over j (thread t owns j=t). Mask broadcasts over query row i.
  float sc = p[t];
  if (mask[b * s + i] == 1) sc = -1e9f;
  red[t] = sc;
  __syncthreads();
  for (int o = 128; o > 0; o >>= 1) {
    if (t < o) red[t] = fmaxf(red[t], red[t + o]);
    __syncthreads();
  }
  float mx = red[0];
  __syncthreads();
  float e = expf(sc - mx);
  p[t] = e;
  red[t] = e;
  __syncthreads();
  for (int o = 128; o > 0; o >>= 1) {
    if (t < o) red[t] += red[t + o];
    __syncthreads();
  }
  float inv = 1.0f / red[0];

  // Phase B: out[d] = sum_j p[j] * (v[b,h,j,d] + cbv[b,j,i,h,d])
  int d = t & 63;
  int c = t >> 6;  // 0..3
  float acc = 0.0f;
  int chunk = s >> 2;
  for (int jj = 0; jj < chunk; ++jj) {
    int j = c * chunk + jj;
    size_t vb = ((size_t)(b * s + j)) * D_MODEL + h * DK + d;
    size_t bb = (((size_t)(b * s + j)) * s + i) * D_MODEL + h * DK + d;
    acc += p[j] * (v[vb] + cbv[bb]);
  }
  outp[c][d] = acc;
  __syncthreads();
  if (t < DK) {
    float o = (outp[0][t] + outp[1][t] + outp[2][t] + outp[3][t]) * inv;
    concat[((size_t)(b * s + i)) * D_MODEL + h * DK + t] = o;
  }
}

// ---------------- Host launch ----------------
extern "C" void kernel_launch(void* const* d_in, const int* in_sizes, int n_in,
                              void* d_out, int out_size, void* d_ws, size_t ws_size,
                              hipStream_t stream) {
  const float* x      = (const float*)d_in[0];
  const float* cbk    = (const float*)d_in[1];
  const float* cbv    = (const float*)d_in[2];
  const int*   mask   = (const int*)d_in[3];
  const float* Wq     = (const float*)d_in[4];
  const float* bq     = (const float*)d_in[5];
  const float* Wk     = (const float*)d_in[6];
  const float* bk     = (const float*)d_in[7];
  const float* Wv     = (const float*)d_in[8];
  const float* bv     = (const float*)d_in[9];
  const float* Wo     = (const float*)d_in[10];
  const float* bo     = (const float*)d_in[11];
  const float* alpha1 = (const float*)d_in[12];
  const float* beta1  = (const float*)d_in[13];
  const float* alpha2 = (const float*)d_in[14];
  const float* beta2  = (const float*)d_in[15];
  const float* W1     = (const float*)d_in[16];
  const float* b1     = (const float*)d_in[17];
  const float* W2     = (const float*)d_in[18];
  const float* b2     = (const float*)d_in[19];

  int bs = in_sizes[0] / D_MODEL;       // b*s tokens (512)
  int s  = in_sizes[1] / in_sizes[0];   // 256
  int b  = bs / s;                      // 2

  float* ws = (float*)d_ws;
  float* x2      = ws;                       // bs*512
  float* qb      = x2 + (size_t)bs * D_MODEL;
  float* kb      = qb + (size_t)bs * D_MODEL;
  float* vb      = kb + (size_t)bs * D_MODEL;
  float* concat  = vb + (size_t)bs * D_MODEL;
  float* xres    = concat + (size_t)bs * D_MODEL;
  float* x2b     = xres + (size_t)bs * D_MODEL;
  float* f1      = x2b + (size_t)bs * D_MODEL;   // bs*2048
  float* partial = f1 + (size_t)bs * DFFN;       // 4 * bs*512

  // 1. LN1
  ln_kernel<<<bs, 256, 0, stream>>>(x, alpha1, beta1, x2);

  // 2. Q/K/V projections (fused over gridDim.z)
  Triple3 p3;
  p3.t[0] = {Wq, bq, qb};
  p3.t[1] = {Wk, bk, kb};
  p3.t[2] = {Wv, bv, vb};
  gemm_qkv<<<dim3(D_MODEL / 64, bs / 64, 3), 256, 0, stream>>>(x2, p3, bs, D_MODEL, D_MODEL);

  // 3. Attention with connection biases
  attn_kernel<<<b * NHEADS * s, 256, 0, stream>>>(qb, kb, vb, cbk, cbv, mask, concat, s);

  // 4. Output projection + residual
  gemm_nt<0><<<dim3(D_MODEL / 64, bs / 64), 256, 0, stream>>>(
      concat, Wo, bo, x, xres, bs, D_MODEL, D_MODEL);

  // 5. LN2
  ln_kernel<<<bs, 256, 0, stream>>>(xres, alpha2, beta2, x2b);

  // 6. FFN1 + ReLU
  gemm_nt<1><<<dim3(DFFN / 64, bs / 64), 256, 0, stream>>>(
      x2b, W1, b1, nullptr, f1, bs, DFFN, D_MODEL);

  // 7. FFN2 split-K (K=2048 over 4 chunks) + reduce epilogue with bias+residual
  gemm_nt_splitk<<<dim3(D_MODEL / 64, bs / 64, 4), 256, 0, stream>>>(
      f1, W2, partial, bs, D_MODEL, DFFN, DFFN / 4);
  splitk_reduce<<<(bs * D_MODEL + 255) / 256, 256, 0, stream>>>(
      partial, b2, xres, (float*)d_out, bs * D_MODEL, D_MODEL, 4);
}

// Round 2
// 609.629 us; speedup vs baseline: 1.1939x; 1.1939x over previous
//
#include <hip/hip_runtime.h>
#include <math.h>

#define D_MODEL 512
#define NHEADS 8
#define DK 64
#define DFFN 2048

typedef __attribute__((ext_vector_type(8))) __bf16 bf16x8;
typedef __attribute__((ext_vector_type(4))) float floatx4;

// ============ LayerNorm: one block per row, out = bf16 ============
__global__ __launch_bounds__(256) void ln_kernel(
    const float* __restrict__ x, const float* __restrict__ alpha,
    const float* __restrict__ beta, __bf16* __restrict__ y) {
  int row = blockIdx.x;
  int t = threadIdx.x;
  const float* xr = x + (size_t)row * D_MODEL;
  float2 v = ((const float2*)xr)[t];
  __shared__ float rs[256], rq[256];
  rs[t] = v.x + v.y;
  rq[t] = v.x * v.x + v.y * v.y;
  __syncthreads();
  for (int o = 128; o > 0; o >>= 1) {
    if (t < o) { rs[t] += rs[t + o]; rq[t] += rq[t + o]; }
    __syncthreads();
  }
  float mu = rs[0] * (1.0f / D_MODEL);
  // ddof=1 variance; denominator (sd + eps) matches jnp.std + EPS
  float var = (rq[0] - (float)D_MODEL * mu * mu) * (1.0f / (D_MODEL - 1));
  float inv = 1.0f / (sqrtf(fmaxf(var, 0.0f)) + 1e-6f);
  float2 a2 = ((const float2*)alpha)[t];
  float2 b2 = ((const float2*)beta)[t];
  union { __bf16 h2[2]; unsigned int u; } pk;
  pk.h2[0] = (__bf16)(a2.x * (v.x - mu) * inv + b2.x);
  pk.h2[1] = (__bf16)(a2.y * (v.y - mu) * inv + b2.y);
  *(unsigned int*)(y + (size_t)row * D_MODEL + 2 * t) = pk.u;
}

// ============ fp32 -> bf16 cast, 6 segments, vectorized x4 ============
struct Seg { const float* src; __bf16* dst; int n4; };  // n4 = n/4
struct Segs6 { Seg s[6]; };
__global__ __launch_bounds__(256) void cast6(Segs6 cs) {
  Seg sg = cs.s[blockIdx.y];
  int stride = gridDim.x * 256;
  for (int idx = blockIdx.x * 256 + threadIdx.x; idx < sg.n4; idx += stride) {
    float4 f = ((const float4*)sg.src)[idx];
    union { __bf16 h[4]; uint2 u; } pk;
    pk.h[0] = (__bf16)f.x; pk.h[1] = (__bf16)f.y;
    pk.h[2] = (__bf16)f.z; pk.h[3] = (__bf16)f.w;
    ((uint2*)sg.dst)[idx] = pk.u;
  }
}

__global__ __launch_bounds__(256) void pack_bias(
    const float* __restrict__ bq, const float* __restrict__ bk,
    const float* __restrict__ bv, float* __restrict__ dst) {
  int idx = blockIdx.x * 256 + threadIdx.x;
  if (idx >= 3 * D_MODEL) return;
  float v = idx < 512 ? bq[idx] : (idx < 1024 ? bk[idx - 512] : bv[idx - 1024]);
  dst[idx] = v;
}

// ============ Wave-level bf16 MFMA GEMM ============
// C[m,n] = sum_k A[m,k] * B[n,k] + bias[n] (+ res) (opt relu, opt bf16 out)
// One wave (64 thr) per 32x32 tile, 2x2 fragments of 16x16x32.
// A,B L2-resident -> no LDS staging, direct 16-B fragment loads.
// Layout (m89/m91-verified): A-frag lane holds A[m=lane&15][k=quad*8+j];
// B-frag from row n of B (== B^T col); D: col=lane&15, row=quad*4+reg.
template <int RELU, int OUT_BF16>
__global__ __launch_bounds__(64) void wave_gemm(
    const __bf16* __restrict__ A, int lda, const __bf16* __restrict__ B, int ldb,
    const float* __restrict__ bias, const float* __restrict__ res,
    void* __restrict__ Cv, int N, int K) {
  int lane = threadIdx.x;
  int r16 = lane & 15;
  int ko = (lane >> 4) * 8;
  int m0 = blockIdx.y * 32, n0 = blockIdx.x * 32;
  const __bf16* A0 = A + (size_t)(m0 + r16) * lda + ko;
  const __bf16* A1 = A0 + (size_t)16 * lda;
  const __bf16* B0 = B + (size_t)(n0 + r16) * ldb + ko;
  const __bf16* B1 = B0 + (size_t)16 * ldb;
  floatx4 acc00 = {0.f, 0.f, 0.f, 0.f};
  floatx4 acc01 = acc00, acc10 = acc00, acc11 = acc00;
#pragma unroll 4
  for (int k0 = 0; k0 < K; k0 += 32) {
    bf16x8 a0 = *(const bf16x8*)(A0 + k0);
    bf16x8 a1 = *(const bf16x8*)(A1 + k0);
    bf16x8 b0 = *(const bf16x8*)(B0 + k0);
    bf16x8 b1 = *(const bf16x8*)(B1 + k0);
    acc00 = __builtin_amdgcn_mfma_f32_16x16x32_bf16(a0, b0, acc00, 0, 0, 0);
    acc01 = __builtin_amdgcn_mfma_f32_16x16x32_bf16(a0, b1, acc01, 0, 0, 0);
    acc10 = __builtin_amdgcn_mfma_f32_16x16x32_bf16(a1, b0, acc10, 0, 0, 0);
    acc11 = __builtin_amdgcn_mfma_f32_16x16x32_bf16(a1, b1, acc11, 0, 0, 0);
  }
  int col = lane & 15, rb = (lane >> 4) * 4;
  floatx4 accs[2][2] = {{acc00, acc01}, {acc10, acc11}};
#pragma unroll
  for (int i = 0; i < 2; ++i) {
#pragma unroll
    for (int j = 0; j < 2; ++j) {
#pragma unroll
      for (int r = 0; r < 4; ++r) {
        int row = m0 + i * 16 + rb + r;
        int cc = n0 + j * 16 + col;
        float v = accs[i][j][r] + bias[cc];
        if (res) v += res[(size_t)row * N + cc];
        if (RELU) v = fmaxf(v, 0.0f);
        if (OUT_BF16)
          ((__bf16*)Cv)[(size_t)row * N + cc] = (__bf16)v;
        else
          ((float*)Cv)[(size_t)row * N + cc] = v;
      }
    }
  }
}

// ============ Attention: one block per (b,i), ALL 8 heads ============
// cbk[b,j,i,:] and cbv[b,j,i,:] are contiguous 2-KB reads (32 B/lane).
// qkv: [bs][1536] fp32 (cols 0..511=q, 512..1023=k, 1024..1535=v), L2-hot.
__global__ __launch_bounds__(256) void attn_kernel(
    const float* __restrict__ qkv, int ldq,
    const float* __restrict__ cbk, const float* __restrict__ cbv,
    const int* __restrict__ mask, __bf16* __restrict__ concat, int s) {
  int i = blockIdx.x % s;
  int b = blockIdx.x / s;
  int t = threadIdx.x;
  int w = t >> 6;        // wave 0..3, owns j in [w*64, w*64+64)
  int lane = t & 63;     // lane owns d in [lane*8, lane*8+8); head h = lane>>3
  int h = lane >> 3;

  __shared__ float sc[NHEADS][257];  // scores then p; 257 -> conflict-free
  __shared__ float sums[NHEADS];
  __shared__ float part[4][D_MODEL];

  size_t tok_i = (size_t)(b * s + i);
  const float* qp = qkv + tok_i * ldq + lane * 8;
  float4 q0 = *(const float4*)(qp);
  float4 q1 = *(const float4*)(qp + 4);

  // ---- Phase A: scores[h][j] = (q . (k_j + cbk)) / 8
  for (int jj = 0; jj < 64; ++jj) {
    int j = w * 64 + jj;
    size_t tok_j = (size_t)(b * s + j);
    const float* kp = qkv + tok_j * ldq + 512 + lane * 8;
    const float* cp = cbk + (tok_j * s + i) * D_MODEL + lane * 8;
    float4 k0 = *(const float4*)(kp);
    float4 k1 = *(const float4*)(kp + 4);
    float4 c0 = *(const float4*)(cp);
    float4 c1 = *(const float4*)(cp + 4);
    float d = q0.x * (k0.x + c0.x) + q0.y * (k0.y + c0.y) +
              q0.z * (k0.z + c0.z) + q0.w * (k0.w + c0.w) +
              q1.x * (k1.x + c1.x) + q1.y * (k1.y + c1.y) +
              q1.z * (k1.z + c1.z) + q1.w * (k1.w + c1.w);
    d += __shfl_xor(d, 1);
    d += __shfl_xor(d, 2);
    d += __shfl_xor(d, 4);
    if ((lane & 7) == 0) sc[h][j] = d * 0.125f;
  }
  __syncthreads();

  // ---- Phase S: per-head softmax. Wave w handles heads 2w, 2w+1 (32 lanes each).
  {
    int hh = 2 * w + (lane >> 5);
    int l32 = lane & 31;
    bool masked = (mask[b * s + i] == 1);
    float vals[8];
    float mx = -1e30f;
#pragma unroll
    for (int kk = 0; kk < 8; ++kk) {
      float xv = sc[hh][l32 + kk * 32];
      if (masked) xv = -1e9f;
      vals[kk] = xv;
      mx = fmaxf(mx, xv);
    }
    for (int m = 1; m < 32; m <<= 1) mx = fmaxf(mx, __shfl_xor(mx, m, 32));
    float ls = 0.f;
#pragma unroll
    for (int kk = 0; kk < 8; ++kk) {
      float e = expf(vals[kk] - mx);
      sc[hh][l32 + kk * 32] = e;
      ls += e;
    }
    for (int m = 1; m < 32; m <<= 1) ls += __shfl_xor(ls, m, 32);
    if (l32 == 0) sums[hh] = ls;
  }
  __syncthreads();

  // ---- Phase B: out[d] = sum_j p[h][j] * (v_j[d] + cbv[d])
  float4 a0 = {0.f, 0.f, 0.f, 0.f};
  float4 a1 = {0.f, 0.f, 0.f, 0.f};
  for (int jj = 0; jj < 64; ++jj) {
    int j = w * 64 + jj;
    size_t tok_j = (size_t)(b * s + j);
    const float* vp = qkv + tok_j * ldq + 1024 + lane * 8;
    const float* cp = cbv + (tok_j * s + i) * D_MODEL + lane * 8;
    float4 v0 = *(const float4*)(vp);
    float4 v1 = *(const float4*)(vp + 4);
    float4 c0 = *(const float4*)(cp);
    float4 c1 = *(const float4*)(cp + 4);
    float pj = sc[h][j];
    a0.x += pj * (v0.x + c0.x); a0.y += pj * (v0.y + c0.y);
    a0.z += pj * (v0.z + c0.z); a0.w += pj * (v0.w + c0.w);
    a1.x += pj * (v1.x + c1.x); a1.y += pj * (v1.y + c1.y);
    a1.z += pj * (v1.z + c1.z); a1.w += pj * (v1.w + c1.w);
  }
  *(float4*)&part[w][lane * 8] = a0;
  *(float4*)&part[w][lane * 8 + 4] = a1;
  __syncthreads();

  // ---- Final: reduce 4 waves, scale by 1/sum, write bf16
  int d0 = t * 2;
  float inv = 1.0f / sums[d0 >> 6];
  float o0 = (part[0][d0] + part[1][d0] + part[2][d0] + part[3][d0]) * inv;
  float o1 = (part[0][d0 + 1] + part[1][d0 + 1] + part[2][d0 + 1] + part[3][d0 + 1]) * inv;
  union { __bf16 h2[2]; unsigned int u; } pk;
  pk.h2[0] = (__bf16)o0;
  pk.h2[1] = (__bf16)o1;
  *(unsigned int*)(concat + tok_i * D_MODEL + d0) = pk.u;
}

// ============ Host launch ============
extern "C" void kernel_launch(void* const* d_in, const int* in_sizes, int n_in,
                              void* d_out, int out_size, void* d_ws, size_t ws_size,
                              hipStream_t stream) {
  const float* x      = (const float*)d_in[0];
  const float* cbk    = (const float*)d_in[1];
  const float* cbv    = (const float*)d_in[2];
  const int*   mask   = (const int*)d_in[3];
  const float* Wq     = (const float*)d_in[4];
  const float* bq     = (const float*)d_in[5];
  const float* Wk     = (const float*)d_in[6];
  const float* bk     = (const float*)d_in[7];
  const float* Wv     = (const float*)d_in[8];
  const float* bv     = (const float*)d_in[9];
  const float* Wo     = (const float*)d_in[10];
  const float* bo     = (const float*)d_in[11];
  const float* alpha1 = (const float*)d_in[12];
  const float* beta1  = (const float*)d_in[13];
  const float* alpha2 = (const float*)d_in[14];
  const float* beta2  = (const float*)d_in[15];
  const float* W1     = (const float*)d_in[16];
  const float* b1     = (const float*)d_in[17];
  const float* W2     = (const float*)d_in[18];
  const float* b2     = (const float*)d_in[19];

  int bs = in_sizes[0] / D_MODEL;       // 512 tokens
  int s  = in_sizes[1] / in_sizes[0];   // 256

  // Workspace carve (256-B aligned chunks)
  char* wp = (char*)d_ws;
  auto carve = [&](size_t bytes) {
    char* p = wp;
    wp += (bytes + 255) & ~(size_t)255;
    return p;
  };
  __bf16* x2    = (__bf16*)carve((size_t)bs * D_MODEL * 2);
  __bf16* wqkv  = (__bf16*)carve((size_t)3 * D_MODEL * D_MODEL * 2);
  __bf16* wo_b  = (__bf16*)carve((size_t)D_MODEL * D_MODEL * 2);
  __bf16* w1_b  = (__bf16*)carve((size_t)DFFN * D_MODEL * 2);
  __bf16* w2_b  = (__bf16*)carve((size_t)D_MODEL * DFFN * 2);
  float*  bqkv  = (float*)carve((size_t)3 * D_MODEL * 4);
  float*  qkv   = (float*)carve((size_t)bs * 3 * D_MODEL * 4);
  __bf16* conc  = (__bf16*)carve((size_t)bs * D_MODEL * 2);
  float*  xres  = (float*)carve((size_t)bs * D_MODEL * 4);
  __bf16* x2b   = (__bf16*)carve((size_t)bs * D_MODEL * 2);
  __bf16* f1    = (__bf16*)carve((size_t)bs * DFFN * 2);

  // 1. Cast all weights to bf16 (Wq/Wk/Wv packed into one [1536][512])
  Segs6 cs;
  cs.s[0] = {Wq, wqkv,                 D_MODEL * D_MODEL / 4};
  cs.s[1] = {Wk, wqkv + D_MODEL * D_MODEL,     D_MODEL * D_MODEL / 4};
  cs.s[2] = {Wv, wqkv + 2 * D_MODEL * D_MODEL, D_MODEL * D_MODEL / 4};
  cs.s[3] = {Wo, wo_b, D_MODEL * D_MODEL / 4};
  cs.s[4] = {W1, w1_b, DFFN * D_MODEL / 4};
  cs.s[5] = {W2, w2_b, D_MODEL * DFFN / 4};
  cast6<<<dim3(256, 6), 256, 0, stream>>>(cs);
  pack_bias<<<6, 256, 0, stream>>>(bq, bk, bv, bqkv);

  // 2. LN1 -> bf16
  ln_kernel<<<bs, 256, 0, stream>>>(x, alpha1, beta1, x2);

  // 3. Fused QKV GEMM: [512,512] @ [1536,512]^T -> qkv [512][1536] fp32
  wave_gemm<0, 0><<<dim3(3 * D_MODEL / 32, bs / 32), 64, 0, stream>>>(
      x2, D_MODEL, wqkv, D_MODEL, bqkv, nullptr, qkv, 3 * D_MODEL, D_MODEL);

  // 4. Attention (all heads per block) -> concat bf16
  attn_kernel<<<bs, 256, 0, stream>>>(qkv, 3 * D_MODEL, cbk, cbv, mask, conc, s);

  // 5. Wo GEMM + residual(x) -> xres fp32
  wave_gemm<0, 0><<<dim3(D_MODEL / 32, bs / 32), 64, 0, stream>>>(
      conc, D_MODEL, wo_b, D_MODEL, bo, x, xres, D_MODEL, D_MODEL);

  // 6. LN2 -> bf16
  ln_kernel<<<bs, 256, 0, stream>>>(xres, alpha2, beta2, x2b);

  // 7. FFN1 + ReLU -> f1 bf16
  wave_gemm<1, 1><<<dim3(DFFN / 32, bs / 32), 64, 0, stream>>>(
      x2b, D_MODEL, w1_b, D_MODEL, b1, nullptr, f1, DFFN, D_MODEL);

  // 8. FFN2 + bias + residual(xres) -> d_out fp32
  wave_gemm<0, 0><<<dim3(D_MODEL / 32, bs / 32), 64, 0, stream>>>(
      f1, DFFN, w2_b, DFFN, b2, xres, d_out, D_MODEL, DFFN);
}